// Round 2
// baseline (410.297 us; speedup 1.0000x reference)
//
#include <hip/hip_runtime.h>
#include <hip/hip_bf16.h>

// Problem constants
#define NB   256
#define NC   4096
#define NF   64
#define NG   512
#define NH   128
#define NELEM (NB*NC)            // 1048576
#define NSEG  (NB*NG + 1)        // 131073
#define LDX  66                  // row stride of x_with_meta in floats
#define NEGV (-1000000000.0f)
#define TPB_TILES 8              // 64-row tiles per block
#define GRID_MLP (NELEM/64/TPB_TILES)   // 2048

typedef __attribute__((ext_vector_type(8))) short short8;
typedef __attribute__((ext_vector_type(4))) float f32x4;

__device__ __forceinline__ unsigned short f2bf(float f) {
    unsigned u = __float_as_uint(f);
    unsigned r = (u + 0x7FFFu + ((u >> 16) & 1u)) >> 16;
    return (unsigned short)r;
}
__device__ __forceinline__ unsigned encf(float f) {
    unsigned u = __float_as_uint(f);
    return (u & 0x80000000u) ? ~u : (u | 0x80000000u);
}
__device__ __forceinline__ float decf(unsigned u) {
    unsigned v = (u & 0x80000000u) ? (u ^ 0x80000000u) : ~u;
    return __uint_as_float(v);
}

// ---- kernel 0: weight prep -------------------------------------------------
// W0T: [h=128][f=64] bf16 linear (A-frag source for swapped GEMM1)
// W1Ts: [j=128][16 units of 8 bf16], unit index XOR-swizzled: u' = u ^ (j&7)
__global__ void k_prep(const float* __restrict__ W0, const float* __restrict__ W1,
                       unsigned short* __restrict__ W0T, unsigned short* __restrict__ W1Ts) {
    int i = blockIdx.x * 256 + threadIdx.x;
    if (i < 8192) {                       // W0T[j][k] = W0[k][j]
        int j = i >> 6, k = i & 63;
        W0T[i] = f2bf(W0[k * NH + j]);
    } else if (i < 8192 + 16384) {        // W1Ts swizzled: elem (j, c)
        int i2 = i - 8192;
        int j = i2 >> 7, c = i2 & 127;
        int u = c >> 3, d = c & 7;
        W1Ts[(j * 16 + (u ^ (j & 7))) * 8 + d] = f2bf(W1[c * NH + j]);
    }
}

// ---- kernel 1: fused MLP + segment atomics ---------------------------------
__global__ __launch_bounds__(256, 2) void k_mlp(
        const float* __restrict__ X,
        const unsigned short* __restrict__ W0T,
        const unsigned short* __restrict__ W1Ts,
        const float* __restrict__ b0, const float* __restrict__ b1,
        const float* __restrict__ W2, const float* __restrict__ b2p,
        float* __restrict__ rawOut, float2* __restrict__ meta2,
        unsigned* __restrict__ segCnt, float* __restrict__ segSum,
        unsigned* __restrict__ segMax) {
    __shared__ __align__(16) unsigned short sWs1[16384];   // 32 KB, swizzled units
    __shared__ __align__(16) unsigned short sHs[4][2048];  // 4 KB per wave (16 rows x 16 units)
    __shared__ float sB0[128];

    const int t = threadIdx.x, w = t >> 6, l = t & 63;
    const int l15 = l & 15, g = l >> 4;

    // stage W1Ts -> LDS (pre-swizzled, plain linear copy; once per block)
    {
        const uint4* src = (const uint4*)W1Ts;
        uint4* dst = (uint4*)sWs1;
#pragma unroll
        for (int i = 0; i < 8; ++i) dst[i * 256 + t] = src[i * 256 + t];
    }
    if (t < 128) sB0[t] = b0[t];

    // loop-invariant register fragments
    short8 w0f[8][2];
#pragma unroll
    for (int n = 0; n < 8; ++n)
#pragma unroll
        for (int kk = 0; kk < 2; ++kk)
            w0f[n][kk] = *(const short8*)(W0T + (n * 16 + l15) * 64 + kk * 32 + g * 8);
    float b1v[8], w2v[8];
#pragma unroll
    for (int n = 0; n < 8; ++n) { b1v[n] = b1[n * 16 + l15]; w2v[n] = W2[n * 16 + l15]; }
    const float b2v = b2p[0];

    __syncthreads();   // only barrier

    const int rowbase0 = blockIdx.x * (TPB_TILES * 64) + w * 16;
    unsigned short* hs = sHs[w];
    const int rx = l15 & 7;

    // prefetch feats for tile 0: lane holds row (base+l15), cols kk*32+g*8+0..7
    float2 f[8];
    {
        const float* src = X + (size_t)(rowbase0 + l15) * LDX + g * 8;
#pragma unroll
        for (int kk = 0; kk < 2; ++kk)
#pragma unroll
            for (int i = 0; i < 4; ++i)
                f[kk * 4 + i] = *(const float2*)(src + kk * 32 + i * 2);
    }

    for (int tau = 0; tau < TPB_TILES; ++tau) {
        const int rowb = rowbase0 + tau * 64;

        // convert feats to B-frags
        short8 bfr[2];
#pragma unroll
        for (int kk = 0; kk < 2; ++kk) {
            union { short8 s; unsigned u[4]; } tu;
#pragma unroll
            for (int i = 0; i < 4; ++i) {
                float2 v = f[kk * 4 + i];
                tu.u[i] = (unsigned)f2bf(v.x) | ((unsigned)f2bf(v.y) << 16);
            }
            bfr[kk] = tu.s;
        }
        // prefetch next tile's feats (in flight during both GEMMs)
        if (tau + 1 < TPB_TILES) {
            const float* src = X + (size_t)(rowb + 64 + l15) * LDX + g * 8;
#pragma unroll
            for (int kk = 0; kk < 2; ++kk)
#pragma unroll
                for (int i = 0; i < 4; ++i)
                    f[kk * 4 + i] = *(const float2*)(src + kk * 32 + i * 2);
        }

        // GEMM1 (swapped): D[i=hcol][j=row] ; lane holds h1[row l15][col n*16+g*4+q]
        f32x4 acc[8];
#pragma unroll
        for (int n = 0; n < 8; ++n) acc[n] = (f32x4){0.f, 0.f, 0.f, 0.f};
#pragma unroll
        for (int n = 0; n < 8; ++n) {
            acc[n] = __builtin_amdgcn_mfma_f32_16x16x32_bf16(w0f[n][0], bfr[0], acc[n], 0, 0, 0);
            acc[n] = __builtin_amdgcn_mfma_f32_16x16x32_bf16(w0f[n][1], bfr[1], acc[n], 0, 0, 0);
        }

        // bias+relu, pack pairs, write own-wave Hs (XOR-swizzled 16B units)
#pragma unroll
        for (int n = 0; n < 8; ++n) {
#pragma unroll
            for (int p = 0; p < 2; ++p) {
                int c0 = n * 16 + g * 4 + 2 * p;
                float h0 = fmaxf(acc[n][2 * p]     + sB0[c0],     0.f);
                float h1 = fmaxf(acc[n][2 * p + 1] + sB0[c0 + 1], 0.f);
                unsigned pk = (unsigned)f2bf(h0) | ((unsigned)f2bf(h1) << 16);
                int u = c0 >> 3;
                *(unsigned*)(hs + (l15 * 16 + (u ^ rx)) * 8 + (c0 & 7)) = pk;
            }
        }

        // read A2-frags: lane needs h1[row l15][kk*32+g*8+0..7]
        short8 a2[4];
#pragma unroll
        for (int kk = 0; kk < 4; ++kk) {
            int u = kk * 4 + g;
            a2[kk] = *(const short8*)(hs + (l15 * 16 + (u ^ rx)) * 8);
        }

        // GEMM2: h2 = h1 @ W1 ; B-frags from swizzled LDS
        f32x4 acc2[8];
#pragma unroll
        for (int n = 0; n < 8; ++n) acc2[n] = (f32x4){0.f, 0.f, 0.f, 0.f};
#pragma unroll
        for (int n = 0; n < 8; ++n) {
            const unsigned short* wrow = sWs1 + (n * 16 + l15) * 128;  // row&7 == l15&7
#pragma unroll
            for (int kk = 0; kk < 4; ++kk) {
                int u = kk * 4 + g;
                short8 bb = *(const short8*)(wrow + (u ^ rx) * 8);
                acc2[n] = __builtin_amdgcn_mfma_f32_16x16x32_bf16(a2[kk], bb, acc2[n], 0, 0, 0);
            }
        }

        // epilogue: relu + W2 dot (cols n*16+l15), reduce over l15
        float rq[4] = {0.f, 0.f, 0.f, 0.f};
#pragma unroll
        for (int n = 0; n < 8; ++n) {
#pragma unroll
            for (int q = 0; q < 4; ++q)
                rq[q] += fmaxf(acc2[n][q] + b1v[n], 0.f) * w2v[n];
        }
#pragma unroll
        for (int off = 1; off < 16; off <<= 1) {
#pragma unroll
            for (int q = 0; q < 4; ++q) rq[q] += __shfl_xor(rq[q], off, 64);
        }
        if (l15 == 0) {
#pragma unroll
            for (int q = 0; q < 4; ++q) {
                size_t m = (size_t)rowb + g * 4 + q;
                float rv = rq[q] + b2v;
                rawOut[m] = rv;
                float2 mt = *(const float2*)(X + m * LDX + 64);
                meta2[m] = mt;
                int gid = (int)mt.x;
                if (mt.y > 0.f && gid >= 0) {
                    int seg = (int)(m >> 12) * NG + gid;
                    atomicAdd(&segCnt[seg], 1u);
                    atomicAdd(&segSum[seg], rv);
                    atomicMax(&segMax[seg], encf(rv));
                }
            }
        }
    }
}

// ---- kernel 2: per-segment stats + bias MLP --------------------------------
__global__ void k_seg(const unsigned* __restrict__ cnt, const float* __restrict__ sum,
                      const unsigned* __restrict__ mx,
                      const float* __restrict__ Wb0, const float* __restrict__ bb0,
                      const float* __restrict__ Wb1, const float* __restrict__ bb1,
                      float4* __restrict__ segstats) {
    int s = blockIdx.x * 256 + threadIdx.x;
    if (s >= NSEG) return;
    unsigned c = cnt[s];
    float smax = (c > 0) ? decf(mx[s]) : 0.f;
    float mean = sum[s] / fmaxf((float)c, 1.f);
    float multi = (c > 1) ? 1.f : 0.f;
    float bias = 0.f;
    if (c > 1) {
        float s0 = smax, s1 = mean, s2 = (float)c;
        bias = bb1[0];
#pragma unroll
        for (int j = 0; j < 32; ++j) {
            float h = s0 * Wb0[j] + s1 * Wb0[32 + j] + s2 * Wb0[64 + j] + bb0[j];
            bias += fmaxf(h, 0.f) * Wb1[j];
        }
    }
    segstats[s] = make_float4(smax, mean, bias, multi);
}

// ---- kernel 3: gather + fair/mask writeout ---------------------------------
__global__ void k_final(const float* __restrict__ raw, const float2* __restrict__ meta2,
                        const float4* __restrict__ segstats, float* __restrict__ out) {
    size_t m = (size_t)blockIdx.x * 256 + threadIdx.x;
    float rv = raw[m];
    float2 mt = meta2[m];
    int gid = (int)mt.x;
    float fair;
    if (mt.y > 0.f) {
        fair = rv;
        if (gid >= 0) {
            int seg = (int)(m >> 12) * NG + gid;
            float4 st = segstats[seg];
            if (st.w > 0.5f) fair = 1.5f * rv - st.y + 0.5f * st.x + st.z;
        }
    } else {
        fair = NEGV;
    }
    out[m] = fair;
    out[NELEM + m] = mt.y;
}

// ---- launch ----------------------------------------------------------------
extern "C" void kernel_launch(void* const* d_in, const int* in_sizes, int n_in,
                              void* d_out, int out_size, void* d_ws, size_t ws_size,
                              hipStream_t stream) {
    const float* X   = (const float*)d_in[0];
    const float* W0  = (const float*)d_in[1];
    const float* b0  = (const float*)d_in[2];
    const float* W1  = (const float*)d_in[3];
    const float* b1  = (const float*)d_in[4];
    const float* W2  = (const float*)d_in[5];
    const float* b2  = (const float*)d_in[6];
    const float* Wb0 = (const float*)d_in[7];
    const float* bb0 = (const float*)d_in[8];
    const float* Wb1 = (const float*)d_in[9];
    const float* bb1 = (const float*)d_in[10];

    char* ws = (char*)d_ws;
    float*          raw      = (float*)(ws + 0);                 //  4 MB
    float2*         meta2    = (float2*)(ws + 4194304);          //  8 MB
    float4*         segstats = (float4*)(ws + 12582912);         //  2 MB
    unsigned*       cnt      = (unsigned*)(ws + 14680080);
    float*          sum      = (float*)(ws + 15204372);
    unsigned*       mx       = (unsigned*)(ws + 15728664);
    unsigned short* W0T      = (unsigned short*)(ws + 16252960); // 16 KB
    unsigned short* W1Ts     = (unsigned short*)(ws + 16269344); // 32 KB

    hipMemsetAsync(ws + 14680080, 0, 3u * 524292u, stream);      // cnt+sum+mx
    k_prep<<<96, 256, 0, stream>>>(W0, W1, W0T, W1Ts);
    k_mlp<<<GRID_MLP, 256, 0, stream>>>(X, W0T, W1Ts, b0, b1, W2, b2,
                                        raw, meta2, cnt, sum, mx);
    k_seg<<<(NSEG + 255) / 256, 256, 0, stream>>>(cnt, sum, mx, Wb0, bb0, Wb1, bb1, segstats);
    k_final<<<NELEM / 256, 256, 0, stream>>>(raw, meta2, segstats, (float*)d_out);
}

// Round 3
// 163.379 us; speedup vs baseline: 2.5113x; 2.5113x over previous
//
#include <hip/hip_runtime.h>
#include <hip/hip_bf16.h>

// Problem constants
#define NB   256
#define NC   4096
#define NF   64
#define NG   512
#define NH   128
#define NELEM (NB*NC)            // 1048576
#define NSEG  (NB*NG + 1)        // 131073
#define LDX  66                  // row stride of x_with_meta in floats
#define NEGV (-1000000000.0f)
#define TILES 8                  // 128-row tiles per block
#define TILE_ROWS 128
#define GRID_MLP (NELEM/(TILES*TILE_ROWS))   // 1024

typedef __attribute__((ext_vector_type(8))) short short8;
typedef __attribute__((ext_vector_type(4))) float f32x4;

__device__ __forceinline__ unsigned short f2bf(float f) {
    unsigned u = __float_as_uint(f);
    unsigned r = (u + 0x7FFFu + ((u >> 16) & 1u)) >> 16;
    return (unsigned short)r;
}
__device__ __forceinline__ unsigned encf(float f) {
    unsigned u = __float_as_uint(f);
    return (u & 0x80000000u) ? ~u : (u | 0x80000000u);
}
__device__ __forceinline__ float decf(unsigned u) {
    unsigned v = (u & 0x80000000u) ? (u ^ 0x80000000u) : ~u;
    return __uint_as_float(v);
}

// ---- kernel 0: weight prep -------------------------------------------------
// W0T: [h=128][f=64] bf16 linear (A-frag source for swapped GEMM1)
// W1Ts: [j=128][16 units of 8 bf16], unit index XOR-swizzled: u' = u ^ (j&7)
__global__ void k_prep(const float* __restrict__ W0, const float* __restrict__ W1,
                       unsigned short* __restrict__ W0T, unsigned short* __restrict__ W1Ts) {
    int i = blockIdx.x * 256 + threadIdx.x;
    if (i < 8192) {                       // W0T[j][k] = W0[k][j]
        int j = i >> 6, k = i & 63;
        W0T[i] = f2bf(W0[k * NH + j]);
    } else if (i < 8192 + 16384) {        // W1Ts swizzled: elem (j, c)
        int i2 = i - 8192;
        int j = i2 >> 7, c = i2 & 127;
        int u = c >> 3, d = c & 7;
        W1Ts[(j * 16 + (u ^ (j & 7))) * 8 + d] = f2bf(W1[c * NH + j]);
    }
}

// ---- kernel 1: fused MLP + segment atomics ---------------------------------
// Block: 4 waves x 32 rows = 128-row tiles, TILES per block, barrier-free loop.
__global__ __launch_bounds__(256, 2) void k_mlp(
        const float* __restrict__ X,
        const unsigned short* __restrict__ W0T,
        const unsigned short* __restrict__ W1Ts,
        const float* __restrict__ b0, const float* __restrict__ b1,
        const float* __restrict__ W2, const float* __restrict__ b2p,
        float* __restrict__ rawOut, float2* __restrict__ meta2,
        unsigned* __restrict__ segCnt, float* __restrict__ segSum,
        unsigned* __restrict__ segMax) {
    __shared__ __align__(16) unsigned short sWs1[16384];     // 32 KB W1 frags (swizzled)
    __shared__ __align__(16) unsigned short sBuf[4][4096];   // 8 KB per wave: feats/Hs aliased
    __shared__ float sB0[128];
    __shared__ float2 sMeta[4][2][32];                        // per-wave meta, double-buffered

    const int t = threadIdx.x, w = t >> 6, l = t & 63;
    const int l15 = l & 15, g = l >> 4;
    const int rx = l15 & 7;

    // stage W1 (pre-swizzled, linear copy; once per block)
    {
        const uint4* src = (const uint4*)W1Ts;
        uint4* dst = (uint4*)sWs1;
#pragma unroll
        for (int i = 0; i < 8; ++i) dst[i * 256 + t] = src[i * 256 + t];
    }
    if (t < 128) sB0[t] = b0[t];

    // loop-invariant register fragments
    short8 w0f[8][2];
#pragma unroll
    for (int n = 0; n < 8; ++n)
#pragma unroll
        for (int kk = 0; kk < 2; ++kk)
            w0f[n][kk] = *(const short8*)(W0T + (n * 16 + l15) * 64 + kk * 32 + g * 8);
    float b1v[8], w2v[8];
#pragma unroll
    for (int n = 0; n < 8; ++n) { b1v[n] = b1[n * 16 + l15]; w2v[n] = W2[n * 16 + l15]; }
    const float b2v = b2p[0];

    __syncthreads();   // only barrier: sWs1/sB0 ready

    unsigned short* buf = sBuf[w];
    const size_t rowwave0 = (size_t)blockIdx.x * (TILES * TILE_ROWS) + w * 32;
    const int sr = l >> 1, sc = l & 1;   // staging role: row sr, col-half sc

    // ---- prologue: stage tile 0 (coalesced f32 -> bf16 -> own-wave LDS) ----
    float2 pf[16];
    float2 mt;
    {
        const float* src = X + (rowwave0 + sr) * LDX + sc * 32;
#pragma unroll
        for (int i = 0; i < 16; ++i) pf[i] = *(const float2*)(src + 2 * i);
        if (sc == 1) mt = *(const float2*)(X + (rowwave0 + sr) * LDX + 64);
    }
    {
        unsigned pk[16];
#pragma unroll
        for (int i = 0; i < 16; ++i)
            pk[i] = (unsigned)f2bf(pf[i].x) | ((unsigned)f2bf(pf[i].y) << 16);
        unsigned short* d = buf + sr * 72 + sc * 32;
#pragma unroll
        for (int i = 0; i < 4; ++i)
            ((uint4*)d)[i] = make_uint4(pk[4*i], pk[4*i+1], pk[4*i+2], pk[4*i+3]);
        if (sc == 1) sMeta[w][0][sr] = mt;
    }

    for (int tau = 0; tau < TILES; ++tau) {
        const size_t rowb = rowwave0 + (size_t)tau * TILE_ROWS;

        // 0: issue next tile's global loads (in flight across whole iteration)
        if (tau + 1 < TILES) {
            const float* src = X + (rowb + TILE_ROWS + sr) * LDX + sc * 32;
#pragma unroll
            for (int i = 0; i < 16; ++i) pf[i] = *(const float2*)(src + 2 * i);
            if (sc == 1) mt = *(const float2*)(X + (rowb + TILE_ROWS + sr) * LDX + 64);
        }

        // 1: feats fragments (row rg*16+l15, cols kk*32+g*8..+7)
        short8 bfr[2][2];
#pragma unroll
        for (int rg = 0; rg < 2; ++rg)
#pragma unroll
            for (int kk = 0; kk < 2; ++kk)
                bfr[rg][kk] = *(const short8*)(buf + (rg * 16 + l15) * 72 + kk * 32 + g * 8);

        // 2: GEMM1 (swapped): D[hcol][row]; one B-frag feeds 8 n-blocks
        f32x4 acc[8][2];
#pragma unroll
        for (int n = 0; n < 8; ++n)
#pragma unroll
            for (int rg = 0; rg < 2; ++rg) acc[n][rg] = (f32x4){0.f, 0.f, 0.f, 0.f};
#pragma unroll
        for (int n = 0; n < 8; ++n)
#pragma unroll
            for (int rg = 0; rg < 2; ++rg) {
                acc[n][rg] = __builtin_amdgcn_mfma_f32_16x16x32_bf16(w0f[n][0], bfr[rg][0], acc[n][rg], 0, 0, 0);
                acc[n][rg] = __builtin_amdgcn_mfma_f32_16x16x32_bf16(w0f[n][1], bfr[rg][1], acc[n][rg], 0, 0, 0);
            }

        // 3: bias+relu -> bf16 Hs (XOR-swizzled 16B units, b64 stores), over buf
#pragma unroll
        for (int n = 0; n < 8; ++n) {
            const int c0 = n * 16 + g * 4;
            const float bv0 = sB0[c0], bv1 = sB0[c0+1], bv2 = sB0[c0+2], bv3 = sB0[c0+3];
            const int u = (2 * n + (g >> 1)) ^ rx;
#pragma unroll
            for (int rg = 0; rg < 2; ++rg) {
                unsigned p01 = (unsigned)f2bf(fmaxf(acc[n][rg][0] + bv0, 0.f))
                             | ((unsigned)f2bf(fmaxf(acc[n][rg][1] + bv1, 0.f)) << 16);
                unsigned p23 = (unsigned)f2bf(fmaxf(acc[n][rg][2] + bv2, 0.f))
                             | ((unsigned)f2bf(fmaxf(acc[n][rg][3] + bv3, 0.f)) << 16);
                *(uint2*)(buf + ((rg * 16 + l15) * 16 + u) * 8 + (g & 1) * 4) = make_uint2(p01, p23);
            }
        }

        // 4: A2 fragments (row rg*16+l15, cols kk*32+g*8..+7, swizzled)
        short8 a2[2][4];
#pragma unroll
        for (int rg = 0; rg < 2; ++rg)
#pragma unroll
            for (int kk = 0; kk < 4; ++kk)
                a2[rg][kk] = *(const short8*)(buf + ((rg * 16 + l15) * 16 + ((kk * 4 + g) ^ rx)) * 8);

        // 5: write next tile's feats into buf (aliases Hs; all Hs reads done)
        if (tau + 1 < TILES) {
            unsigned pk[16];
#pragma unroll
            for (int i = 0; i < 16; ++i)
                pk[i] = (unsigned)f2bf(pf[i].x) | ((unsigned)f2bf(pf[i].y) << 16);
            unsigned short* d = buf + sr * 72 + sc * 32;
#pragma unroll
            for (int i = 0; i < 4; ++i)
                ((uint4*)d)[i] = make_uint4(pk[4*i], pk[4*i+1], pk[4*i+2], pk[4*i+3]);
            if (sc == 1) sMeta[w][(tau + 1) & 1][sr] = mt;
        }

        // 6: GEMM2 + fused epilogue dot (B-frag shared across both row-groups)
        float rq[2][4] = {{0.f,0.f,0.f,0.f},{0.f,0.f,0.f,0.f}};
#pragma unroll
        for (int n = 0; n < 8; ++n) {
            f32x4 acc2[2] = {(f32x4){0.f,0.f,0.f,0.f}, (f32x4){0.f,0.f,0.f,0.f}};
            const unsigned short* wrow = sWs1 + (n * 16 + l15) * 128;
#pragma unroll
            for (int kk = 0; kk < 4; ++kk) {
                short8 bb = *(const short8*)(wrow + (((kk * 4 + g)) ^ rx) * 8);
                acc2[0] = __builtin_amdgcn_mfma_f32_16x16x32_bf16(a2[0][kk], bb, acc2[0], 0, 0, 0);
                acc2[1] = __builtin_amdgcn_mfma_f32_16x16x32_bf16(a2[1][kk], bb, acc2[1], 0, 0, 0);
            }
#pragma unroll
            for (int rg = 0; rg < 2; ++rg)
#pragma unroll
                for (int q = 0; q < 4; ++q)
                    rq[rg][q] += fmaxf(acc2[rg][q] + b1v[n], 0.f) * w2v[n];
        }

        // 7: reduce over l15 (h2 cols), store, atomics
#pragma unroll
        for (int off = 1; off < 16; off <<= 1)
#pragma unroll
            for (int rg = 0; rg < 2; ++rg)
#pragma unroll
                for (int q = 0; q < 4; ++q)
                    rq[rg][q] += __shfl_xor(rq[rg][q], off, 64);
        if (l15 == 0) {
#pragma unroll
            for (int rg = 0; rg < 2; ++rg) {
                const size_t m0 = rowb + rg * 16 + g * 4;
                float4 rv = make_float4(rq[rg][0] + b2v, rq[rg][1] + b2v,
                                        rq[rg][2] + b2v, rq[rg][3] + b2v);
                *(float4*)(rawOut + m0) = rv;
                float2 mts[4];
#pragma unroll
                for (int j = 0; j < 4; ++j) mts[j] = sMeta[w][tau & 1][rg * 16 + g * 4 + j];
                ((float4*)(meta2 + m0))[0] = make_float4(mts[0].x, mts[0].y, mts[1].x, mts[1].y);
                ((float4*)(meta2 + m0))[1] = make_float4(mts[2].x, mts[2].y, mts[3].x, mts[3].y);
                const int bidx = (int)(m0 >> 12);
                const float rvs[4] = {rv.x, rv.y, rv.z, rv.w};
#pragma unroll
                for (int j = 0; j < 4; ++j) {
                    int gid = (int)mts[j].x;
                    if (mts[j].y > 0.f && gid >= 0) {
                        int seg = bidx * NG + gid;
                        atomicAdd(&segCnt[seg], 1u);
                        atomicAdd(&segSum[seg], rvs[j]);
                        atomicMax(&segMax[seg], encf(rvs[j]));
                    }
                }
            }
        }
    }
}

// ---- kernel 2: per-segment stats + bias MLP --------------------------------
__global__ void k_seg(const unsigned* __restrict__ cnt, const float* __restrict__ sum,
                      const unsigned* __restrict__ mx,
                      const float* __restrict__ Wb0, const float* __restrict__ bb0,
                      const float* __restrict__ Wb1, const float* __restrict__ bb1,
                      float4* __restrict__ segstats) {
    int s = blockIdx.x * 256 + threadIdx.x;
    if (s >= NSEG) return;
    unsigned c = cnt[s];
    float smax = (c > 0) ? decf(mx[s]) : 0.f;
    float mean = sum[s] / fmaxf((float)c, 1.f);
    float multi = (c > 1) ? 1.f : 0.f;
    float bias = 0.f;
    if (c > 1) {
        float s0 = smax, s1 = mean, s2 = (float)c;
        bias = bb1[0];
#pragma unroll
        for (int j = 0; j < 32; ++j) {
            float h = s0 * Wb0[j] + s1 * Wb0[32 + j] + s2 * Wb0[64 + j] + bb0[j];
            bias += fmaxf(h, 0.f) * Wb1[j];
        }
    }
    segstats[s] = make_float4(smax, mean, bias, multi);
}

// ---- kernel 3: gather + fair/mask writeout (4 elems/thread) -----------------
__global__ void k_final(const float4* __restrict__ raw4, const float4* __restrict__ meta4,
                        const float4* __restrict__ segstats, float* __restrict__ out) {
    int i = blockIdx.x * 256 + threadIdx.x;         // group of 4 elems
    float4 rv = raw4[i];
    float4 mA = meta4[2 * i], mB = meta4[2 * i + 1];
    const float r[4]   = {rv.x, rv.y, rv.z, rv.w};
    const float gidf[4]= {mA.x, mA.z, mB.x, mB.z};
    const float msk[4] = {mA.y, mA.w, mB.y, mB.w};
    const size_t m0 = (size_t)i * 4;
    const int bidx = (int)(m0 >> 12);
    float fair[4];
#pragma unroll
    for (int j = 0; j < 4; ++j) {
        int gid = (int)gidf[j];
        float f;
        if (msk[j] > 0.f) {
            f = r[j];
            if (gid >= 0) {
                float4 st = segstats[bidx * NG + gid];
                if (st.w > 0.5f) f = 1.5f * r[j] - st.y + 0.5f * st.x + st.z;
            }
        } else {
            f = NEGV;
        }
        fair[j] = f;
    }
    *(float4*)(out + m0) = make_float4(fair[0], fair[1], fair[2], fair[3]);
    *(float4*)(out + NELEM + m0) = make_float4(msk[0], msk[1], msk[2], msk[3]);
}

// ---- launch ----------------------------------------------------------------
extern "C" void kernel_launch(void* const* d_in, const int* in_sizes, int n_in,
                              void* d_out, int out_size, void* d_ws, size_t ws_size,
                              hipStream_t stream) {
    const float* X   = (const float*)d_in[0];
    const float* W0  = (const float*)d_in[1];
    const float* b0  = (const float*)d_in[2];
    const float* W1  = (const float*)d_in[3];
    const float* b1  = (const float*)d_in[4];
    const float* W2  = (const float*)d_in[5];
    const float* b2  = (const float*)d_in[6];
    const float* Wb0 = (const float*)d_in[7];
    const float* bb0 = (const float*)d_in[8];
    const float* Wb1 = (const float*)d_in[9];
    const float* bb1 = (const float*)d_in[10];

    char* ws = (char*)d_ws;
    float*          raw      = (float*)(ws + 0);                 //  4 MB
    float2*         meta2    = (float2*)(ws + 4194304);          //  8 MB
    float4*         segstats = (float4*)(ws + 12582912);         //  2 MB
    unsigned*       cnt      = (unsigned*)(ws + 14680080);
    float*          sum      = (float*)(ws + 15204372);
    unsigned*       mx       = (unsigned*)(ws + 15728664);
    unsigned short* W0T      = (unsigned short*)(ws + 16252960); // 16 KB
    unsigned short* W1Ts     = (unsigned short*)(ws + 16269344); // 32 KB

    hipMemsetAsync(ws + 14680080, 0, 3u * 524292u, stream);      // cnt+sum+mx
    k_prep<<<96, 256, 0, stream>>>(W0, W1, W0T, W1Ts);
    k_mlp<<<GRID_MLP, 256, 0, stream>>>(X, W0T, W1Ts, b0, b1, W2, b2,
                                        raw, meta2, cnt, sum, mx);
    k_seg<<<(NSEG + 255) / 256, 256, 0, stream>>>(cnt, sum, mx, Wb0, bb0, Wb1, bb1, segstats);
    k_final<<<NELEM / 1024, 256, 0, stream>>>((const float4*)raw, (const float4*)meta2,
                                              segstats, (float*)d_out);
}